// Round 7
// baseline (393.414 us; speedup 1.0000x reference)
//
#include <hip/hip_runtime.h>

#define F_IN   512
#define HD     64     // H*D layer-1 output width
#define NHEAD  8
#define NC     40     // classes
#define NEG    0.2f

typedef __attribute__((ext_vector_type(8))) short bf16x8;
typedef __attribute__((ext_vector_type(4))) float f32x4;

__device__ __forceinline__ float lrelu(float x) { return x > 0.0f ? x : NEG * x; }

__device__ __forceinline__ short f2bf(float f) {
    unsigned u = __float_as_uint(f);
    u += 0x7FFF + ((u >> 16) & 1);   // RNE to bf16
    return (short)(u >> 16);
}
__device__ __forceinline__ float bf2f(short h) {
    return __uint_as_float(((unsigned)(unsigned short)h) << 16);
}
__device__ __forceinline__ float bfl(unsigned u) { return __uint_as_float(u << 16); }
__device__ __forceinline__ float bfh(unsigned u) { return __uint_as_float(u & 0xFFFF0000u); }

// ---------------- CSR build ----------------
__global__ void zero_kernel(int* __restrict__ p, int n) {
    int i = blockIdx.x * 256 + threadIdx.x;
    if (i < n) p[i] = 0;
}

__global__ void count_kernel(const int* __restrict__ dst, int* __restrict__ deg,
                             int* __restrict__ pos, int E) {
    int e = blockIdx.x * 256 + threadIdx.x;
    if (e < E) pos[e] = atomicAdd(&deg[dst[e]], 1);
}

__global__ __launch_bounds__(256) void scanA_kernel(const int* __restrict__ deg,
                                                    int* __restrict__ incl,
                                                    int* __restrict__ bsum, int Nn) {
    __shared__ int wsum[4];
    int t = threadIdx.x, b = blockIdx.x;
    int base = b * 1024 + t * 4;
    int v0 = (base + 0) < Nn ? deg[base + 0] : 0;
    int v1 = (base + 1) < Nn ? deg[base + 1] : 0;
    int v2 = (base + 2) < Nn ? deg[base + 2] : 0;
    int v3 = (base + 3) < Nn ? deg[base + 3] : 0;
    int p0 = v0, p1 = p0 + v1, p2 = p1 + v2, p3 = p2 + v3;
    int lane = t & 63, w = t >> 6;
    int sc = p3;
    for (int off = 1; off < 64; off <<= 1) {
        int u = __shfl_up(sc, off);
        if (lane >= off) sc += u;
    }
    if (lane == 63) wsum[w] = sc;
    __syncthreads();
    int woff = 0;
#pragma unroll
    for (int i = 0; i < 4; ++i) if (i < w) woff += wsum[i];
    int excl = woff + sc - p3;
    if (base + 0 < Nn) incl[base + 0] = excl + p0;
    if (base + 1 < Nn) incl[base + 1] = excl + p1;
    if (base + 2 < Nn) incl[base + 2] = excl + p2;
    if (base + 3 < Nn) incl[base + 3] = excl + p3;
    if (t == 0) bsum[b] = wsum[0] + wsum[1] + wsum[2] + wsum[3];
}

__global__ void scanB_kernel(int* __restrict__ bsum, int nb) {
    int lane = threadIdx.x;  // 64 threads
    int a = lane < nb ? bsum[lane] : 0;
    int c = (lane + 64) < nb ? bsum[lane + 64] : 0;
    int sa = a, sc2 = c;
    for (int off = 1; off < 64; off <<= 1) {
        int u = __shfl_up(sa, off);  if (lane >= off) sa += u;
        int u2 = __shfl_up(sc2, off); if (lane >= off) sc2 += u2;
    }
    int totA = __shfl(sa, 63);
    int ea = sa - a;
    int ec = totA + sc2 - c;
    if (lane < nb) bsum[lane] = ea;
    if (lane + 64 < nb) bsum[lane + 64] = ec;
}

__global__ void scanC_kernel(const int* __restrict__ incl, const int* __restrict__ bsum,
                             int* __restrict__ rp, int Nn) {
    int i = blockIdx.x * 256 + threadIdx.x;
    if (i == 0) rp[0] = 0;
    if (i < Nn) rp[i + 1] = incl[i] + bsum[i >> 10];
}

// ---------------- g1s: fused GEMM1(MFMA)+alpha1 epilogue  ||  scatter ----------
// blocks [0, nG1): gemm1 (128 rows each); blocks [nG1, nG1+nSC): CSR scatter.
// gemm1: A (x) loaded directly from global into fragments (row=lane&15,
// k=(lane>>4)*8+j), bf16 in-register (lo-part dropped). W split hi+lo in LDS
// B[kgrp][col][8] (conflict-free b128). Hp written as bf16.
#define G1_BM 128
__global__ __launch_bounds__(256) void g1s_kernel(const float* __restrict__ X,
                                                  const float* __restrict__ W,
                                                  const float* __restrict__ att_s,
                                                  const float* __restrict__ att_d,
                                                  unsigned short* __restrict__ Hp,
                                                  float* __restrict__ as1,
                                                  float* __restrict__ ad1,
                                                  const int* __restrict__ src,
                                                  const int* __restrict__ dst,
                                                  const int* __restrict__ pos,
                                                  const int* __restrict__ rp,
                                                  int* __restrict__ col,
                                                  int Nn, int E, int nG1) {
    __shared__ short Bh[4][HD][8];   // [kgrp][col][kk&7]
    __shared__ short Bl[4][HD][8];
    int tid = threadIdx.x;

    if ((int)blockIdx.x >= nG1) {
        int e = ((int)blockIdx.x - nG1) * 256 + tid;
        if (e < E) {
            int d = dst[e];
            int p = rp[d] + pos[e];
            __builtin_nontemporal_store(src[e], &col[p]);
        }
        return;
    }

    int wid = tid >> 6, lane = tid & 63;
    int lrow = lane & 15, kgrp = lane >> 4;
    int row0 = blockIdx.x * G1_BM;
    int rowA = row0 + wid * 32 + lrow;   // fr adds 16

    int sc = tid & 63, skc = tid >> 6;   // B staging: col, k-chunk

    float ats[4], atd[4];
#pragma unroll
    for (int fc = 0; fc < 4; ++fc) { ats[fc] = att_s[fc * 16 + lrow]; atd[fc] = att_d[fc * 16 + lrow]; }

    f32x4 acc[2][4];
#pragma unroll
    for (int fr = 0; fr < 2; ++fr)
#pragma unroll
        for (int fc = 0; fc < 4; ++fc) acc[fr][fc] = (f32x4){0.f, 0.f, 0.f, 0.f};

    float4 a_cur[2][2], a_nxt[2][2];
#pragma unroll
    for (int fr = 0; fr < 2; ++fr) {
        int gr = rowA + fr * 16;
        if (gr < Nn) {
            const float* p = X + (size_t)gr * F_IN + kgrp * 8;
            a_cur[fr][0] = *reinterpret_cast<const float4*>(p);
            a_cur[fr][1] = *reinterpret_cast<const float4*>(p + 4);
        } else {
            a_cur[fr][0] = a_cur[fr][1] = make_float4(0.f, 0.f, 0.f, 0.f);
        }
    }

    for (int it = 0; it < F_IN / 32; ++it) {
        int k0 = it * 32;
        float wreg[8];
#pragma unroll
        for (int j = 0; j < 8; ++j)
            wreg[j] = W[(size_t)(k0 + skc * 8 + j) * HD + sc];
        if (it + 1 < F_IN / 32) {
#pragma unroll
            for (int fr = 0; fr < 2; ++fr) {
                int gr = rowA + fr * 16;
                if (gr < Nn) {
                    const float* p = X + (size_t)gr * F_IN + (k0 + 32) + kgrp * 8;
                    a_nxt[fr][0] = *reinterpret_cast<const float4*>(p);
                    a_nxt[fr][1] = *reinterpret_cast<const float4*>(p + 4);
                } else {
                    a_nxt[fr][0] = a_nxt[fr][1] = make_float4(0.f, 0.f, 0.f, 0.f);
                }
            }
        }
        bf16x8 af[2];
#pragma unroll
        for (int fr = 0; fr < 2; ++fr) {
            float fs[8] = {a_cur[fr][0].x, a_cur[fr][0].y, a_cur[fr][0].z, a_cur[fr][0].w,
                           a_cur[fr][1].x, a_cur[fr][1].y, a_cur[fr][1].z, a_cur[fr][1].w};
#pragma unroll
            for (int j = 0; j < 8; ++j) af[fr][j] = f2bf(fs[j]);
        }
        __syncthreads();
        {
            bf16x8 vh, vl;
#pragma unroll
            for (int j = 0; j < 8; ++j) {
                short hh = f2bf(wreg[j]);
                vh[j] = hh;
                vl[j] = f2bf(wreg[j] - bf2f(hh));
            }
            *reinterpret_cast<bf16x8*>(&Bh[skc][sc][0]) = vh;
            *reinterpret_cast<bf16x8*>(&Bl[skc][sc][0]) = vl;
        }
        __syncthreads();
        bf16x8 bh[4], bl[4];
#pragma unroll
        for (int fc = 0; fc < 4; ++fc) {
            bh[fc] = *reinterpret_cast<const bf16x8*>(&Bh[kgrp][fc * 16 + lrow][0]);
            bl[fc] = *reinterpret_cast<const bf16x8*>(&Bl[kgrp][fc * 16 + lrow][0]);
        }
#pragma unroll
        for (int fr = 0; fr < 2; ++fr)
#pragma unroll
            for (int fc = 0; fc < 4; ++fc) {
                acc[fr][fc] = __builtin_amdgcn_mfma_f32_16x16x32_bf16(af[fr], bh[fc], acc[fr][fc], 0, 0, 0);
                acc[fr][fc] = __builtin_amdgcn_mfma_f32_16x16x32_bf16(af[fr], bl[fc], acc[fr][fc], 0, 0, 0);
            }
        if (it + 1 < F_IN / 32) {
#pragma unroll
            for (int fr = 0; fr < 2; ++fr) {
                a_cur[fr][0] = a_nxt[fr][0];
                a_cur[fr][1] = a_nxt[fr][1];
            }
        }
    }

    // epilogue: bf16 Hp + fused per-head attention logits (fp32)
#pragma unroll
    for (int fr = 0; fr < 2; ++fr) {
#pragma unroll
        for (int r = 0; r < 4; ++r) {
            int gr = row0 + wid * 32 + fr * 16 + kgrp * 4 + r;
            float hv[4], sp[4], dp[4];
#pragma unroll
            for (int fc = 0; fc < 4; ++fc) {
                hv[fc] = acc[fr][fc][r];
                sp[fc] = hv[fc] * ats[fc];
                dp[fc] = hv[fc] * atd[fc];
            }
#pragma unroll
            for (int mask = 1; mask <= 4; mask <<= 1) {
#pragma unroll
                for (int fc = 0; fc < 4; ++fc) {
                    sp[fc] += __shfl_xor(sp[fc], mask);
                    dp[fc] += __shfl_xor(dp[fc], mask);
                }
            }
            if (gr < Nn) {
#pragma unroll
                for (int fc = 0; fc < 4; ++fc)
                    Hp[(size_t)gr * HD + fc * 16 + lrow] = (unsigned short)f2bf(hv[fc]);
                if ((lane & 7) == 0) {
                    int hh = lrow >> 3;
#pragma unroll
                    for (int fc = 0; fc < 4; ++fc) {
                        as1[gr * NHEAD + fc * 2 + hh] = sp[fc];
                        ad1[gr * NHEAD + fc * 2 + hh] = dp[fc];
                    }
                }
            }
        }
    }
}

// ---------------- agg1 + fused GEMM2 + alpha2 ----------------
// Wave per node: gather-aggregate bf16 Hp -> h1 (all lanes hold full reduction),
// +bias +ELU; then h2 = h1 @ W2 via shfl-broadcast loop (lane = class),
// as2/ad2 dots, h2p written as packed bf16.
__global__ __launch_bounds__(256) void agg1_kernel(const unsigned short* __restrict__ Hp,
                                                   const float* __restrict__ as1,
                                                   const float* __restrict__ ad1,
                                                   const int* __restrict__ col,
                                                   const int* __restrict__ rp,
                                                   const float* __restrict__ b1,
                                                   const float* __restrict__ W2,
                                                   const float* __restrict__ as2w,
                                                   const float* __restrict__ ad2w,
                                                   unsigned int* __restrict__ h2p,
                                                   float* __restrict__ as2,
                                                   float* __restrict__ ad2, int Nn) {
    __shared__ float W2s[HD][NC];
    __shared__ float asv[NC], adv[NC];
    int tid = threadIdx.x;
    for (int i = tid; i < HD * NC; i += 256) W2s[i / NC][i % NC] = W2[i];
    if (tid < NC) { asv[tid] = as2w[tid]; adv[tid] = ad2w[tid]; }
    __syncthreads();
    int n = blockIdx.x * 4 + (tid >> 6);
    int lane = tid & 63;
    if (n >= Nn) return;
    int slot = lane >> 4, l16 = lane & 15, h = l16 >> 1;
    int beg = rp[n], end = rp[n + 1];
    float adv1 = ad1[n * NHEAD + h];
    float4 acc = make_float4(0.f, 0.f, 0.f, 0.f);
    float dw = 0.f;
    for (int t = beg + slot; t < end; t += 4) {
        int s = col[t];
        float w = __expf(lrelu(as1[s * NHEAD + h] + adv1));
        dw += w;
        uint2 u = *reinterpret_cast<const uint2*>(&Hp[(size_t)s * HD + l16 * 4]);
        acc.x += w * bfl(u.x); acc.y += w * bfh(u.x);
        acc.z += w * bfl(u.y); acc.w += w * bfh(u.y);
    }
#pragma unroll
    for (int mask = 16; mask < 64; mask <<= 1) {
        acc.x += __shfl_xor(acc.x, mask);
        acc.y += __shfl_xor(acc.y, mask);
        acc.z += __shfl_xor(acc.z, mask);
        acc.w += __shfl_xor(acc.w, mask);
        dw    += __shfl_xor(dw, mask);
    }
    // self term + bias + ELU on ALL lanes (all slots identical)
    {
        float w = __expf(lrelu(as1[n * NHEAD + h] + adv1));
        uint2 u = *reinterpret_cast<const uint2*>(&Hp[(size_t)n * HD + l16 * 4]);
        acc.x += w * bfl(u.x); acc.y += w * bfh(u.x);
        acc.z += w * bfl(u.y); acc.w += w * bfh(u.y);
        dw += w;
        float invd = 1.0f / (dw + 1e-16f);
        float4 bb = *reinterpret_cast<const float4*>(&b1[l16 * 4]);
        acc.x = acc.x * invd + bb.x; acc.y = acc.y * invd + bb.y;
        acc.z = acc.z * invd + bb.z; acc.w = acc.w * invd + bb.w;
        acc.x = acc.x > 0.0f ? acc.x : __expf(acc.x) - 1.0f;
        acc.y = acc.y > 0.0f ? acc.y : __expf(acc.y) - 1.0f;
        acc.z = acc.z > 0.0f ? acc.z : __expf(acc.z) - 1.0f;
        acc.w = acc.w > 0.0f ? acc.w : __expf(acc.w) - 1.0f;
    }
    // fused GEMM2: lane = class c
    int cw = lane < NC ? lane : 0;
    float h2 = 0.f;
#pragma unroll
    for (int k = 0; k < HD; ++k) {
        int srcl = k >> 2;
        float comp = (k & 3) == 0 ? acc.x : (k & 3) == 1 ? acc.y : (k & 3) == 2 ? acc.z : acc.w;
        float hk = __shfl(comp, srcl);
        h2 += hk * W2s[k][cw];
    }
    float sa = lane < NC ? h2 * asv[lane] : 0.f;
    float da = lane < NC ? h2 * adv[lane] : 0.f;
#pragma unroll
    for (int mask = 1; mask < 64; mask <<= 1) { sa += __shfl_xor(sa, mask); da += __shfl_xor(da, mask); }
    if (lane == 0) { as2[n] = sa; ad2[n] = da; }
    float hp2 = __shfl(h2, lane + 1);
    if (lane < NC && !(lane & 1)) {
        unsigned int u = ((unsigned int)(unsigned short)f2bf(hp2) << 16) |
                         (unsigned short)f2bf(h2);
        h2p[(size_t)n * 20 + (lane >> 1)] = u;
    }
}

// ---------------- agg2: bf16 gather + bias + log_softmax ----------------
__global__ __launch_bounds__(256) void agg2_kernel(const unsigned int* __restrict__ h2p,
                                                   const float* __restrict__ as2,
                                                   const float* __restrict__ ad2,
                                                   const int* __restrict__ col,
                                                   const int* __restrict__ rp,
                                                   const float* __restrict__ b2,
                                                   float* __restrict__ out, int Nn) {
    int n = blockIdx.x * 4 + (threadIdx.x >> 6);
    int lane = threadIdx.x & 63;
    if (n >= Nn) return;
    int slot = lane >> 4, l16 = lane & 15;
    bool act = l16 < 10;
    int beg = rp[n], end = rp[n + 1];
    float adv = ad2[n];
    float4 acc = make_float4(0.f, 0.f, 0.f, 0.f);
    float dw = 0.f;
    for (int t = beg + slot; t < end; t += 4) {
        int s = col[t];
        float w = __expf(lrelu(as2[s] + adv));
        dw += w;
        if (act) {
            uint2 u = *reinterpret_cast<const uint2*>(&h2p[(size_t)s * 20 + l16 * 2]);
            acc.x += w * bfl(u.x); acc.y += w * bfh(u.x);
            acc.z += w * bfl(u.y); acc.w += w * bfh(u.y);
        }
    }
#pragma unroll
    for (int mask = 16; mask < 64; mask <<= 1) {
        acc.x += __shfl_xor(acc.x, mask);
        acc.y += __shfl_xor(acc.y, mask);
        acc.z += __shfl_xor(acc.z, mask);
        acc.w += __shfl_xor(acc.w, mask);
        dw    += __shfl_xor(dw, mask);
    }
    float w = __expf(lrelu(as2[n] + adv));
    dw += w;
    float invd = 1.0f / (dw + 1e-16f);
    if (act) {
        uint2 u = *reinterpret_cast<const uint2*>(&h2p[(size_t)n * 20 + l16 * 2]);
        float4 bb = *reinterpret_cast<const float4*>(&b2[l16 * 4]);
        acc.x = (acc.x + w * bfl(u.x)) * invd + bb.x;
        acc.y = (acc.y + w * bfh(u.x)) * invd + bb.y;
        acc.z = (acc.z + w * bfl(u.y)) * invd + bb.z;
        acc.w = (acc.w + w * bfh(u.y)) * invd + bb.w;
    }
    float mloc = act ? fmaxf(fmaxf(acc.x, acc.y), fmaxf(acc.z, acc.w)) : -INFINITY;
#pragma unroll
    for (int mask = 1; mask < 16; mask <<= 1) mloc = fmaxf(mloc, __shfl_xor(mloc, mask));
    float s4 = act ? (__expf(acc.x - mloc) + __expf(acc.y - mloc) +
                      __expf(acc.z - mloc) + __expf(acc.w - mloc)) : 0.0f;
#pragma unroll
    for (int mask = 1; mask < 16; mask <<= 1) s4 += __shfl_xor(s4, mask);
    float lse = mloc + __logf(s4);
    if (slot == 0 && act) {
        float4 o = make_float4(acc.x - lse, acc.y - lse, acc.z - lse, acc.w - lse);
        *reinterpret_cast<float4*>(&out[(size_t)n * NC + l16 * 4]) = o;
    }
}

extern "C" void kernel_launch(void* const* d_in, const int* in_sizes, int n_in,
                              void* d_out, int out_size, void* d_ws, size_t ws_size,
                              hipStream_t stream) {
    const float* x    = (const float*)d_in[0];
    const int*   ei   = (const int*)d_in[1];
    const float* W1   = (const float*)d_in[2];
    const float* as1w = (const float*)d_in[3];
    const float* ad1w = (const float*)d_in[4];
    const float* b1   = (const float*)d_in[5];
    const float* W2   = (const float*)d_in[6];
    const float* as2w = (const float*)d_in[7];
    const float* ad2w = (const float*)d_in[8];
    const float* b2   = (const float*)d_in[9];
    float* out = (float*)d_out;

    int Nn = in_sizes[0] / F_IN;
    int E  = in_sizes[1] / 2;
    const int* srcv = ei;
    const int* dstv = ei + E;

    char* ws = (char*)d_ws;
    size_t off = 0;
    auto alloc = [&](size_t bytes) { size_t cur = off; off += (bytes + 255) & ~255ULL; return cur; };
    unsigned short* Hp = (unsigned short*)(ws + alloc((size_t)Nn * HD * 2));
    float* as1v = (float*)(ws + alloc((size_t)Nn * NHEAD * 4));
    float* ad1v = (float*)(ws + alloc((size_t)Nn * NHEAD * 4));
    unsigned int* h2p = (unsigned int*)(ws + alloc((size_t)Nn * 20 * 4));
    float* as2v = (float*)(ws + alloc((size_t)Nn * 4));
    float* ad2v = (float*)(ws + alloc((size_t)Nn * 4));
    int* deg  = (int*)(ws + alloc((size_t)Nn * 4));
    int* incl = (int*)(ws + alloc((size_t)Nn * 4));
    int* rp   = (int*)(ws + alloc((size_t)(Nn + 1) * 4));
    int* pos  = (int*)(ws + alloc((size_t)E * 4));
    int* col  = (int*)(ws + alloc((size_t)E * 4));
    int* bsum = (int*)(ws + alloc(256 * 4));

    int nb  = (Nn + 1023) / 1024;
    int nG1 = (Nn + G1_BM - 1) / G1_BM;
    int nSC = (E + 255) / 256;

    zero_kernel<<<(Nn + 255) / 256, 256, 0, stream>>>(deg, Nn);
    count_kernel<<<(E + 255) / 256, 256, 0, stream>>>(dstv, deg, pos, E);
    scanA_kernel<<<nb, 256, 0, stream>>>(deg, incl, bsum, Nn);
    scanB_kernel<<<1, 64, 0, stream>>>(bsum, nb);
    scanC_kernel<<<(Nn + 255) / 256, 256, 0, stream>>>(incl, bsum, rp, Nn);

    g1s_kernel<<<nG1 + nSC, 256, 0, stream>>>(x, W1, as1w, ad1w, Hp, as1v, ad1v,
                                              srcv, dstv, pos, rp, col, Nn, E, nG1);
    agg1_kernel<<<(Nn + 3) / 4, 256, 0, stream>>>(Hp, as1v, ad1v, col, rp, b1,
                                                  W2, as2w, ad2w, h2p, as2v, ad2v, Nn);
    agg2_kernel<<<(Nn + 3) / 4, 256, 0, stream>>>(h2p, as2v, ad2v, col, rp, b2, out, Nn);
}

// Round 8
// 333.373 us; speedup vs baseline: 1.1801x; 1.1801x over previous
//
#include <hip/hip_runtime.h>

#define F_IN   512
#define HD     64     // H*D layer-1 output width
#define NHEAD  8
#define NC     40     // classes
#define NEG    0.2f

typedef __attribute__((ext_vector_type(8))) short bf16x8;
typedef __attribute__((ext_vector_type(4))) float f32x4;

__device__ __forceinline__ float lrelu(float x) { return x > 0.0f ? x : NEG * x; }

__device__ __forceinline__ short f2bf(float f) {
    unsigned u = __float_as_uint(f);
    u += 0x7FFF + ((u >> 16) & 1);   // RNE to bf16
    return (short)(u >> 16);
}
__device__ __forceinline__ float bf2f(short h) {
    return __uint_as_float(((unsigned)(unsigned short)h) << 16);
}
__device__ __forceinline__ float bfl(unsigned u) { return __uint_as_float(u << 16); }
__device__ __forceinline__ float bfh(unsigned u) { return __uint_as_float(u & 0xFFFF0000u); }

// ---------------- CSR build ----------------
__global__ void zero_kernel(int* __restrict__ p, int n) {
    int i = blockIdx.x * 256 + threadIdx.x;
    if (i < n) p[i] = 0;
}

__global__ void count_kernel(const int* __restrict__ dst, int* __restrict__ deg,
                             int* __restrict__ pos, int E) {
    int e = blockIdx.x * 256 + threadIdx.x;
    if (e < E) pos[e] = atomicAdd(&deg[dst[e]], 1);
}

__global__ __launch_bounds__(256) void scanA_kernel(const int* __restrict__ deg,
                                                    int* __restrict__ incl,
                                                    int* __restrict__ bsum, int Nn) {
    __shared__ int wsum[4];
    int t = threadIdx.x, b = blockIdx.x;
    int base = b * 1024 + t * 4;
    int v0 = (base + 0) < Nn ? deg[base + 0] : 0;
    int v1 = (base + 1) < Nn ? deg[base + 1] : 0;
    int v2 = (base + 2) < Nn ? deg[base + 2] : 0;
    int v3 = (base + 3) < Nn ? deg[base + 3] : 0;
    int p0 = v0, p1 = p0 + v1, p2 = p1 + v2, p3 = p2 + v3;
    int lane = t & 63, w = t >> 6;
    int sc = p3;
    for (int off = 1; off < 64; off <<= 1) {
        int u = __shfl_up(sc, off);
        if (lane >= off) sc += u;
    }
    if (lane == 63) wsum[w] = sc;
    __syncthreads();
    int woff = 0;
#pragma unroll
    for (int i = 0; i < 4; ++i) if (i < w) woff += wsum[i];
    int excl = woff + sc - p3;
    if (base + 0 < Nn) incl[base + 0] = excl + p0;
    if (base + 1 < Nn) incl[base + 1] = excl + p1;
    if (base + 2 < Nn) incl[base + 2] = excl + p2;
    if (base + 3 < Nn) incl[base + 3] = excl + p3;
    if (t == 0) bsum[b] = wsum[0] + wsum[1] + wsum[2] + wsum[3];
}

__global__ void scanB_kernel(int* __restrict__ bsum, int nb) {
    int lane = threadIdx.x;  // 64 threads
    int a = lane < nb ? bsum[lane] : 0;
    int c = (lane + 64) < nb ? bsum[lane + 64] : 0;
    int sa = a, sc2 = c;
    for (int off = 1; off < 64; off <<= 1) {
        int u = __shfl_up(sa, off);  if (lane >= off) sa += u;
        int u2 = __shfl_up(sc2, off); if (lane >= off) sc2 += u2;
    }
    int totA = __shfl(sa, 63);
    int ea = sa - a;
    int ec = totA + sc2 - c;
    if (lane < nb) bsum[lane] = ea;
    if (lane + 64 < nb) bsum[lane + 64] = ec;
}

__global__ void scanC_kernel(const int* __restrict__ incl, const int* __restrict__ bsum,
                             int* __restrict__ rp, int Nn) {
    int i = blockIdx.x * 256 + threadIdx.x;
    if (i == 0) rp[0] = 0;
    if (i < Nn) rp[i + 1] = incl[i] + bsum[i >> 10];
}

// ---------------- g1s: fused GEMM1(MFMA)+alpha1 epilogue  ||  scatter ----------
// blocks [0, nG1): gemm1 (64 rows each); blocks [nG1, nG1+nSC): CSR scatter.
// BM=64 (4 waves x 16 rows) for grid occupancy; BK=64 (2 barriers / 64 K).
#define G1_BM 64
__global__ __launch_bounds__(256) void g1s_kernel(const float* __restrict__ X,
                                                  const float* __restrict__ W,
                                                  const float* __restrict__ att_s,
                                                  const float* __restrict__ att_d,
                                                  unsigned short* __restrict__ Hp,
                                                  float* __restrict__ as1,
                                                  float* __restrict__ ad1,
                                                  const int* __restrict__ src,
                                                  const int* __restrict__ dst,
                                                  const int* __restrict__ pos,
                                                  const int* __restrict__ rp,
                                                  int* __restrict__ col,
                                                  int Nn, int E, int nG1) {
    __shared__ short Bh[2][4][HD][8];   // [ksub][kgrp][col][idx]
    __shared__ short Bl[2][4][HD][8];
    int tid = threadIdx.x;

    if ((int)blockIdx.x >= nG1) {
        int e = ((int)blockIdx.x - nG1) * 256 + tid;
        if (e < E) {
            int d = dst[e];
            int p = rp[d] + pos[e];
            __builtin_nontemporal_store(src[e], &col[p]);
        }
        return;
    }

    int wid = tid >> 6, lane = tid & 63;
    int lrow = lane & 15, kgrp = lane >> 4;
    int row0 = blockIdx.x * G1_BM;
    int rowA = row0 + wid * 16 + lrow;

    int sc = tid & 63, ks = tid >> 6;   // B staging: col, 16-k chunk

    float ats[4], atd[4];
#pragma unroll
    for (int fc = 0; fc < 4; ++fc) { ats[fc] = att_s[fc * 16 + lrow]; atd[fc] = att_d[fc * 16 + lrow]; }

    f32x4 acc[4];
#pragma unroll
    for (int fc = 0; fc < 4; ++fc) acc[fc] = (f32x4){0.f, 0.f, 0.f, 0.f};

    bool valid = rowA < Nn;
    const float* xrow = X + (size_t)rowA * F_IN + kgrp * 8;

    float4 a_cur[2][2], a_nxt[2][2];
#pragma unroll
    for (int kb = 0; kb < 2; ++kb) {
        if (valid) {
            a_cur[kb][0] = *reinterpret_cast<const float4*>(xrow + kb * 32);
            a_cur[kb][1] = *reinterpret_cast<const float4*>(xrow + kb * 32 + 4);
        } else {
            a_cur[kb][0] = a_cur[kb][1] = make_float4(0.f, 0.f, 0.f, 0.f);
        }
    }

    for (int it = 0; it < F_IN / 64; ++it) {
        int k0 = it * 64;
        float wreg[16];
#pragma unroll
        for (int j = 0; j < 16; ++j)
            wreg[j] = W[(size_t)(k0 + ks * 16 + j) * HD + sc];
        if (it + 1 < F_IN / 64) {
#pragma unroll
            for (int kb = 0; kb < 2; ++kb) {
                if (valid) {
                    const float* p = xrow + (k0 + 64) + kb * 32;
                    a_nxt[kb][0] = *reinterpret_cast<const float4*>(p);
                    a_nxt[kb][1] = *reinterpret_cast<const float4*>(p + 4);
                } else {
                    a_nxt[kb][0] = a_nxt[kb][1] = make_float4(0.f, 0.f, 0.f, 0.f);
                }
            }
        }
        bf16x8 af[2];
#pragma unroll
        for (int kb = 0; kb < 2; ++kb) {
            float fs[8] = {a_cur[kb][0].x, a_cur[kb][0].y, a_cur[kb][0].z, a_cur[kb][0].w,
                           a_cur[kb][1].x, a_cur[kb][1].y, a_cur[kb][1].z, a_cur[kb][1].w};
#pragma unroll
            for (int j = 0; j < 8; ++j) af[kb][j] = f2bf(fs[j]);
        }
        __syncthreads();
#pragma unroll
        for (int half = 0; half < 2; ++half) {
            bf16x8 vh, vl;
#pragma unroll
            for (int j = 0; j < 8; ++j) {
                float wv = wreg[half * 8 + j];
                short hh = f2bf(wv);
                vh[j] = hh;
                vl[j] = f2bf(wv - bf2f(hh));
            }
            int kk = ks * 2 + half;           // 8-k chunk index 0..7
            *reinterpret_cast<bf16x8*>(&Bh[kk >> 2][kk & 3][sc][0]) = vh;
            *reinterpret_cast<bf16x8*>(&Bl[kk >> 2][kk & 3][sc][0]) = vl;
        }
        __syncthreads();
#pragma unroll
        for (int kb = 0; kb < 2; ++kb) {
#pragma unroll
            for (int fc = 0; fc < 4; ++fc) {
                bf16x8 bh = *reinterpret_cast<const bf16x8*>(&Bh[kb][kgrp][fc * 16 + lrow][0]);
                bf16x8 bl = *reinterpret_cast<const bf16x8*>(&Bl[kb][kgrp][fc * 16 + lrow][0]);
                acc[fc] = __builtin_amdgcn_mfma_f32_16x16x32_bf16(af[kb], bh, acc[fc], 0, 0, 0);
                acc[fc] = __builtin_amdgcn_mfma_f32_16x16x32_bf16(af[kb], bl, acc[fc], 0, 0, 0);
            }
        }
        if (it + 1 < F_IN / 64) {
#pragma unroll
            for (int kb = 0; kb < 2; ++kb) {
                a_cur[kb][0] = a_nxt[kb][0];
                a_cur[kb][1] = a_nxt[kb][1];
            }
        }
    }

    // epilogue: bf16 Hp + fused per-head attention logits (fp32)
#pragma unroll
    for (int r = 0; r < 4; ++r) {
        int gr = row0 + wid * 16 + kgrp * 4 + r;
        float hv[4], sp[4], dp[4];
#pragma unroll
        for (int fc = 0; fc < 4; ++fc) {
            hv[fc] = acc[fc][r];
            sp[fc] = hv[fc] * ats[fc];
            dp[fc] = hv[fc] * atd[fc];
        }
#pragma unroll
        for (int mask = 1; mask <= 4; mask <<= 1) {
#pragma unroll
            for (int fc = 0; fc < 4; ++fc) {
                sp[fc] += __shfl_xor(sp[fc], mask);
                dp[fc] += __shfl_xor(dp[fc], mask);
            }
        }
        if (gr < Nn) {
#pragma unroll
            for (int fc = 0; fc < 4; ++fc)
                Hp[(size_t)gr * HD + fc * 16 + lrow] = (unsigned short)f2bf(hv[fc]);
            if ((lane & 7) == 0) {
                int hh = lrow >> 3;
#pragma unroll
                for (int fc = 0; fc < 4; ++fc) {
                    as1[gr * NHEAD + fc * 2 + hh] = sp[fc];
                    ad1[gr * NHEAD + fc * 2 + hh] = dp[fc];
                }
            }
        }
    }
}

// ---------------- agg1: 8 slots x 8 lanes; lane = head; fp32 h1 out ----------------
__global__ __launch_bounds__(256) void agg1_kernel(const unsigned short* __restrict__ Hp,
                                                   const float* __restrict__ as1,
                                                   const float* __restrict__ ad1,
                                                   const int* __restrict__ col,
                                                   const int* __restrict__ rp,
                                                   const float* __restrict__ b1,
                                                   float* __restrict__ h1, int Nn) {
    int n = blockIdx.x * 4 + (threadIdx.x >> 6);
    int lane = threadIdx.x & 63;
    if (n >= Nn) return;
    int slot = lane >> 3, j = lane & 7;   // j = head index, owns features j*8..j*8+7
    int beg = rp[n], end = rp[n + 1];
    float adv1 = ad1[n * NHEAD + j];
    float acc[8] = {0, 0, 0, 0, 0, 0, 0, 0};
    float dw = 0.f;
    for (int t = beg + slot; t < end; t += 8) {
        int s = col[t];
        float w = __expf(lrelu(as1[s * NHEAD + j] + adv1));
        dw += w;
        uint4 u = *reinterpret_cast<const uint4*>(&Hp[(size_t)s * HD + j * 8]);
        acc[0] += w * bfl(u.x); acc[1] += w * bfh(u.x);
        acc[2] += w * bfl(u.y); acc[3] += w * bfh(u.y);
        acc[4] += w * bfl(u.z); acc[5] += w * bfh(u.z);
        acc[6] += w * bfl(u.w); acc[7] += w * bfh(u.w);
    }
#pragma unroll
    for (int mask = 8; mask < 64; mask <<= 1) {
#pragma unroll
        for (int i = 0; i < 8; ++i) acc[i] += __shfl_xor(acc[i], mask);
        dw += __shfl_xor(dw, mask);
    }
    // self term + bias + ELU (all lanes; slot 0 writes)
    float w = __expf(lrelu(as1[n * NHEAD + j] + adv1));
    uint4 u = *reinterpret_cast<const uint4*>(&Hp[(size_t)n * HD + j * 8]);
    acc[0] += w * bfl(u.x); acc[1] += w * bfh(u.x);
    acc[2] += w * bfl(u.y); acc[3] += w * bfh(u.y);
    acc[4] += w * bfl(u.z); acc[5] += w * bfh(u.z);
    acc[6] += w * bfl(u.w); acc[7] += w * bfh(u.w);
    dw += w;
    float invd = 1.0f / (dw + 1e-16f);
    float4 b0 = *reinterpret_cast<const float4*>(&b1[j * 8]);
    float4 b4 = *reinterpret_cast<const float4*>(&b1[j * 8 + 4]);
    float bb[8] = {b0.x, b0.y, b0.z, b0.w, b4.x, b4.y, b4.z, b4.w};
#pragma unroll
    for (int i = 0; i < 8; ++i) {
        float v = acc[i] * invd + bb[i];
        acc[i] = v > 0.0f ? v : __expf(v) - 1.0f;
    }
    if (slot == 0) {
        float4 o0 = make_float4(acc[0], acc[1], acc[2], acc[3]);
        float4 o1 = make_float4(acc[4], acc[5], acc[6], acc[7]);
        *reinterpret_cast<float4*>(&h1[(size_t)n * HD + j * 8]) = o0;
        *reinterpret_cast<float4*>(&h1[(size_t)n * HD + j * 8 + 4]) = o1;
    }
}

// ---------------- GEMM2: tiled (64 rows/block) + fused alpha2, bf16 h2p out --------
#define G2R 64
__global__ __launch_bounds__(256) void gemm2_kernel(const float* __restrict__ H1,
                                                    const float* __restrict__ W2,
                                                    const float* __restrict__ asw,
                                                    const float* __restrict__ adw,
                                                    unsigned int* __restrict__ h2p,
                                                    float* __restrict__ as2,
                                                    float* __restrict__ ad2, int Nn) {
    __shared__ float Hs[G2R][HD + 1];
    __shared__ float W2s[HD][NC];
    __shared__ float asv[NC], adv[NC];
    int tid = threadIdx.x;
    for (int i = tid; i < HD * NC; i += 256) W2s[i / NC][i % NC] = W2[i];
    if (tid < NC) { asv[tid] = asw[tid]; adv[tid] = adw[tid]; }
    int row0 = blockIdx.x * G2R;
#pragma unroll
    for (int i = 0; i < 4; ++i) {
        int linear = i * 1024 + tid * 4;
        int r = linear >> 6, c = linear & 63;
        int gr = row0 + r;
        float4 v = make_float4(0.f, 0.f, 0.f, 0.f);
        if (gr < Nn) v = *reinterpret_cast<const float4*>(&H1[(size_t)gr * HD + c]);
        Hs[r][c + 0] = v.x; Hs[r][c + 1] = v.y; Hs[r][c + 2] = v.z; Hs[r][c + 3] = v.w;
    }
    __syncthreads();
    int row = tid >> 2, cg = tid & 3;      // 64 rows x 4 col-groups of 10
    int gr = row0 + row;
    float acc[10];
#pragma unroll
    for (int jj = 0; jj < 10; ++jj) acc[jj] = 0.0f;
    for (int k = 0; k < HD; ++k) {
        float a = Hs[row][k];
#pragma unroll
        for (int jj = 0; jj < 10; ++jj) acc[jj] += a * W2s[k][cg * 10 + jj];
    }
    float sa = 0.0f, da = 0.0f;
#pragma unroll
    for (int jj = 0; jj < 10; ++jj) {
        sa += acc[jj] * asv[cg * 10 + jj];
        da += acc[jj] * adv[cg * 10 + jj];
    }
    sa += __shfl_xor(sa, 1); sa += __shfl_xor(sa, 2);
    da += __shfl_xor(da, 1); da += __shfl_xor(da, 2);
    if (gr < Nn) {
        if (cg == 0) { as2[gr] = sa; ad2[gr] = da; }
#pragma unroll
        for (int jj = 0; jj < 5; ++jj) {
            unsigned int u = ((unsigned int)(unsigned short)f2bf(acc[2 * jj + 1]) << 16) |
                             (unsigned short)f2bf(acc[2 * jj]);
            h2p[(size_t)gr * 20 + cg * 5 + jj] = u;
        }
    }
}

// ---------------- agg2: bf16 gather + bias + log_softmax ----------------
__global__ __launch_bounds__(256) void agg2_kernel(const unsigned int* __restrict__ h2p,
                                                   const float* __restrict__ as2,
                                                   const float* __restrict__ ad2,
                                                   const int* __restrict__ col,
                                                   const int* __restrict__ rp,
                                                   const float* __restrict__ b2,
                                                   float* __restrict__ out, int Nn) {
    int n = blockIdx.x * 4 + (threadIdx.x >> 6);
    int lane = threadIdx.x & 63;
    if (n >= Nn) return;
    int slot = lane >> 4, l16 = lane & 15;
    bool act = l16 < 10;
    int beg = rp[n], end = rp[n + 1];
    float adv = ad2[n];
    float4 acc = make_float4(0.f, 0.f, 0.f, 0.f);
    float dw = 0.f;
    for (int t = beg + slot; t < end; t += 4) {
        int s = col[t];
        float w = __expf(lrelu(as2[s] + adv));
        dw += w;
        if (act) {
            uint2 u = *reinterpret_cast<const uint2*>(&h2p[(size_t)s * 20 + l16 * 2]);
            acc.x += w * bfl(u.x); acc.y += w * bfh(u.x);
            acc.z += w * bfl(u.y); acc.w += w * bfh(u.y);
        }
    }
#pragma unroll
    for (int mask = 16; mask < 64; mask <<= 1) {
        acc.x += __shfl_xor(acc.x, mask);
        acc.y += __shfl_xor(acc.y, mask);
        acc.z += __shfl_xor(acc.z, mask);
        acc.w += __shfl_xor(acc.w, mask);
        dw    += __shfl_xor(dw, mask);
    }
    float w = __expf(lrelu(as2[n] + adv));
    dw += w;
    float invd = 1.0f / (dw + 1e-16f);
    if (act) {
        uint2 u = *reinterpret_cast<const uint2*>(&h2p[(size_t)n * 20 + l16 * 2]);
        float4 bb = *reinterpret_cast<const float4*>(&b2[l16 * 4]);
        acc.x = (acc.x + w * bfl(u.x)) * invd + bb.x;
        acc.y = (acc.y + w * bfh(u.x)) * invd + bb.y;
        acc.z = (acc.z + w * bfl(u.y)) * invd + bb.z;
        acc.w = (acc.w + w * bfh(u.y)) * invd + bb.w;
    }
    float mloc = act ? fmaxf(fmaxf(acc.x, acc.y), fmaxf(acc.z, acc.w)) : -INFINITY;
#pragma unroll
    for (int mask = 1; mask < 16; mask <<= 1) mloc = fmaxf(mloc, __shfl_xor(mloc, mask));
    float s4 = act ? (__expf(acc.x - mloc) + __expf(acc.y - mloc) +
                      __expf(acc.z - mloc) + __expf(acc.w - mloc)) : 0.0f;
#pragma unroll
    for (int mask = 1; mask < 16; mask <<= 1) s4 += __shfl_xor(s4, mask);
    float lse = mloc + __logf(s4);
    if (slot == 0 && act) {
        float4 o = make_float4(acc.x - lse, acc.y - lse, acc.z - lse, acc.w - lse);
        *reinterpret_cast<float4*>(&out[(size_t)n * NC + l16 * 4]) = o;
    }
}

extern "C" void kernel_launch(void* const* d_in, const int* in_sizes, int n_in,
                              void* d_out, int out_size, void* d_ws, size_t ws_size,
                              hipStream_t stream) {
    const float* x    = (const float*)d_in[0];
    const int*   ei   = (const int*)d_in[1];
    const float* W1   = (const float*)d_in[2];
    const float* as1w = (const float*)d_in[3];
    const float* ad1w = (const float*)d_in[4];
    const float* b1   = (const float*)d_in[5];
    const float* W2   = (const float*)d_in[6];
    const float* as2w = (const float*)d_in[7];
    const float* ad2w = (const float*)d_in[8];
    const float* b2   = (const float*)d_in[9];
    float* out = (float*)d_out;

    int Nn = in_sizes[0] / F_IN;
    int E  = in_sizes[1] / 2;
    const int* srcv = ei;
    const int* dstv = ei + E;

    char* ws = (char*)d_ws;
    size_t off = 0;
    auto alloc = [&](size_t bytes) { size_t cur = off; off += (bytes + 255) & ~255ULL; return cur; };
    unsigned short* Hp = (unsigned short*)(ws + alloc((size_t)Nn * HD * 2));
    float* h1   = (float*)(ws + alloc((size_t)Nn * HD * 4));
    float* as1v = (float*)(ws + alloc((size_t)Nn * NHEAD * 4));
    float* ad1v = (float*)(ws + alloc((size_t)Nn * NHEAD * 4));
    unsigned int* h2p = (unsigned int*)(ws + alloc((size_t)Nn * 20 * 4));
    float* as2v = (float*)(ws + alloc((size_t)Nn * 4));
    float* ad2v = (float*)(ws + alloc((size_t)Nn * 4));
    int* deg  = (int*)(ws + alloc((size_t)Nn * 4));
    int* incl = (int*)(ws + alloc((size_t)Nn * 4));
    int* rp   = (int*)(ws + alloc((size_t)(Nn + 1) * 4));
    int* pos  = (int*)(ws + alloc((size_t)E * 4));
    int* col  = (int*)(ws + alloc((size_t)E * 4));
    int* bsum = (int*)(ws + alloc(256 * 4));

    int nb  = (Nn + 1023) / 1024;
    int nG1 = (Nn + G1_BM - 1) / G1_BM;
    int nSC = (E + 255) / 256;

    zero_kernel<<<(Nn + 255) / 256, 256, 0, stream>>>(deg, Nn);
    count_kernel<<<(E + 255) / 256, 256, 0, stream>>>(dstv, deg, pos, E);
    scanA_kernel<<<nb, 256, 0, stream>>>(deg, incl, bsum, Nn);
    scanB_kernel<<<1, 64, 0, stream>>>(bsum, nb);
    scanC_kernel<<<(Nn + 255) / 256, 256, 0, stream>>>(incl, bsum, rp, Nn);

    g1s_kernel<<<nG1 + nSC, 256, 0, stream>>>(x, W1, as1w, ad1w, Hp, as1v, ad1v,
                                              srcv, dstv, pos, rp, col, Nn, E, nG1);
    agg1_kernel<<<(Nn + 3) / 4, 256, 0, stream>>>(Hp, as1v, ad1v, col, rp, b1, h1, Nn);
    gemm2_kernel<<<(Nn + G2R - 1) / G2R, 256, 0, stream>>>(h1, W2, as2w, ad2w, h2p, as2v, ad2v, Nn);
    agg2_kernel<<<(Nn + 3) / 4, 256, 0, stream>>>(h2p, as2v, ad2v, col, rp, b2, out, Nn);
}

// Round 9
// 317.275 us; speedup vs baseline: 1.2400x; 1.0507x over previous
//
#include <hip/hip_runtime.h>

#define F_IN   512
#define HD     64     // H*D layer-1 output width
#define NHEAD  8
#define NC     40     // classes
#define NEG    0.2f

typedef __attribute__((ext_vector_type(8))) short bf16x8;
typedef __attribute__((ext_vector_type(4))) float f32x4;

__device__ __forceinline__ float lrelu(float x) { return x > 0.0f ? x : NEG * x; }

__device__ __forceinline__ short f2bf(float f) {
    unsigned u = __float_as_uint(f);
    u += 0x7FFF + ((u >> 16) & 1);   // RNE to bf16
    return (short)(u >> 16);
}
__device__ __forceinline__ float bf2f(short h) {
    return __uint_as_float(((unsigned)(unsigned short)h) << 16);
}
__device__ __forceinline__ float bfl(unsigned u) { return __uint_as_float(u << 16); }
__device__ __forceinline__ float bfh(unsigned u) { return __uint_as_float(u & 0xFFFF0000u); }

// ---------------- CSR build ----------------
__global__ void zero_kernel(int* __restrict__ p, int n) {
    int i = blockIdx.x * 256 + threadIdx.x;
    if (i < n) p[i] = 0;
}

__global__ __launch_bounds__(256) void scanA_kernel(const int* __restrict__ deg,
                                                    int* __restrict__ incl,
                                                    int* __restrict__ bsum, int Nn) {
    __shared__ int wsum[4];
    int t = threadIdx.x, b = blockIdx.x;
    int base = b * 1024 + t * 4;
    int v0 = (base + 0) < Nn ? deg[base + 0] : 0;
    int v1 = (base + 1) < Nn ? deg[base + 1] : 0;
    int v2 = (base + 2) < Nn ? deg[base + 2] : 0;
    int v3 = (base + 3) < Nn ? deg[base + 3] : 0;
    int p0 = v0, p1 = p0 + v1, p2 = p1 + v2, p3 = p2 + v3;
    int lane = t & 63, w = t >> 6;
    int sc = p3;
    for (int off = 1; off < 64; off <<= 1) {
        int u = __shfl_up(sc, off);
        if (lane >= off) sc += u;
    }
    if (lane == 63) wsum[w] = sc;
    __syncthreads();
    int woff = 0;
#pragma unroll
    for (int i = 0; i < 4; ++i) if (i < w) woff += wsum[i];
    int excl = woff + sc - p3;
    if (base + 0 < Nn) incl[base + 0] = excl + p0;
    if (base + 1 < Nn) incl[base + 1] = excl + p1;
    if (base + 2 < Nn) incl[base + 2] = excl + p2;
    if (base + 3 < Nn) incl[base + 3] = excl + p3;
    if (t == 0) bsum[b] = wsum[0] + wsum[1] + wsum[2] + wsum[3];
}

__global__ void scanB_kernel(int* __restrict__ bsum, int nb) {
    int lane = threadIdx.x;  // 64 threads
    int a = lane < nb ? bsum[lane] : 0;
    int c = (lane + 64) < nb ? bsum[lane + 64] : 0;
    int sa = a, sc2 = c;
    for (int off = 1; off < 64; off <<= 1) {
        int u = __shfl_up(sa, off);  if (lane >= off) sa += u;
        int u2 = __shfl_up(sc2, off); if (lane >= off) sc2 += u2;
    }
    int totA = __shfl(sa, 63);
    int ea = sa - a;
    int ec = totA + sc2 - c;
    if (lane < nb) bsum[lane] = ea;
    if (lane + 64 < nb) bsum[lane + 64] = ec;
}

__global__ void scanC_kernel(const int* __restrict__ incl, const int* __restrict__ bsum,
                             int* __restrict__ rp, int Nn) {
    int i = blockIdx.x * 256 + threadIdx.x;
    if (i == 0) rp[0] = 0;
    if (i < Nn) rp[i + 1] = incl[i] + bsum[i >> 10];
}

// scatter standalone (after scans); regular store -> L2 write coalescing
__global__ void scatter_kernel(const int* __restrict__ src, const int* __restrict__ dst,
                               const int* __restrict__ pos, const int* __restrict__ rp,
                               int* __restrict__ col, int E) {
    int e = blockIdx.x * 256 + threadIdx.x;
    if (e < E) {
        int d = dst[e];
        col[rp[d] + pos[e]] = src[e];
    }
}

// ---------------- g1c: fused GEMM1(MFMA)+alpha1 epilogue  ||  degree count ----------
// blocks [0, nG1): gemm1 (64 rows each); blocks [nG1, nG1+nCNT): count+rank.
#define G1_BM 64
__global__ __launch_bounds__(256) void g1c_kernel(const float* __restrict__ X,
                                                  const float* __restrict__ W,
                                                  const float* __restrict__ att_s,
                                                  const float* __restrict__ att_d,
                                                  unsigned short* __restrict__ Hp,
                                                  float* __restrict__ as1,
                                                  float* __restrict__ ad1,
                                                  const int* __restrict__ dst,
                                                  int* __restrict__ deg,
                                                  int* __restrict__ pos,
                                                  int Nn, int E, int nG1) {
    __shared__ short Bh[2][4][HD][8];   // [ksub][kgrp][col][idx]
    __shared__ short Bl[2][4][HD][8];
    int tid = threadIdx.x;

    if ((int)blockIdx.x >= nG1) {
        int e = ((int)blockIdx.x - nG1) * 256 + tid;
        if (e < E) pos[e] = atomicAdd(&deg[dst[e]], 1);
        return;
    }

    int wid = tid >> 6, lane = tid & 63;
    int lrow = lane & 15, kgrp = lane >> 4;
    int row0 = blockIdx.x * G1_BM;
    int rowA = row0 + wid * 16 + lrow;

    int sc = tid & 63, ks = tid >> 6;   // B staging: col, 16-k chunk

    float ats[4], atd[4];
#pragma unroll
    for (int fc = 0; fc < 4; ++fc) { ats[fc] = att_s[fc * 16 + lrow]; atd[fc] = att_d[fc * 16 + lrow]; }

    f32x4 acc[4];
#pragma unroll
    for (int fc = 0; fc < 4; ++fc) acc[fc] = (f32x4){0.f, 0.f, 0.f, 0.f};

    bool valid = rowA < Nn;
    const float* xrow = X + (size_t)rowA * F_IN + kgrp * 8;

    float4 a_cur[2][2], a_nxt[2][2];
#pragma unroll
    for (int kb = 0; kb < 2; ++kb) {
        if (valid) {
            a_cur[kb][0] = *reinterpret_cast<const float4*>(xrow + kb * 32);
            a_cur[kb][1] = *reinterpret_cast<const float4*>(xrow + kb * 32 + 4);
        } else {
            a_cur[kb][0] = a_cur[kb][1] = make_float4(0.f, 0.f, 0.f, 0.f);
        }
    }

    for (int it = 0; it < F_IN / 64; ++it) {
        int k0 = it * 64;
        float wreg[16];
#pragma unroll
        for (int j = 0; j < 16; ++j)
            wreg[j] = W[(size_t)(k0 + ks * 16 + j) * HD + sc];
        if (it + 1 < F_IN / 64) {
#pragma unroll
            for (int kb = 0; kb < 2; ++kb) {
                if (valid) {
                    const float* p = xrow + (k0 + 64) + kb * 32;
                    a_nxt[kb][0] = *reinterpret_cast<const float4*>(p);
                    a_nxt[kb][1] = *reinterpret_cast<const float4*>(p + 4);
                } else {
                    a_nxt[kb][0] = a_nxt[kb][1] = make_float4(0.f, 0.f, 0.f, 0.f);
                }
            }
        }
        bf16x8 af[2];
#pragma unroll
        for (int kb = 0; kb < 2; ++kb) {
            float fs[8] = {a_cur[kb][0].x, a_cur[kb][0].y, a_cur[kb][0].z, a_cur[kb][0].w,
                           a_cur[kb][1].x, a_cur[kb][1].y, a_cur[kb][1].z, a_cur[kb][1].w};
#pragma unroll
            for (int j = 0; j < 8; ++j) af[kb][j] = f2bf(fs[j]);
        }
        __syncthreads();
#pragma unroll
        for (int half = 0; half < 2; ++half) {
            bf16x8 vh, vl;
#pragma unroll
            for (int j = 0; j < 8; ++j) {
                float wv = wreg[half * 8 + j];
                short hh = f2bf(wv);
                vh[j] = hh;
                vl[j] = f2bf(wv - bf2f(hh));
            }
            int kk = ks * 2 + half;           // 8-k chunk index 0..7
            *reinterpret_cast<bf16x8*>(&Bh[kk >> 2][kk & 3][sc][0]) = vh;
            *reinterpret_cast<bf16x8*>(&Bl[kk >> 2][kk & 3][sc][0]) = vl;
        }
        __syncthreads();
#pragma unroll
        for (int kb = 0; kb < 2; ++kb) {
#pragma unroll
            for (int fc = 0; fc < 4; ++fc) {
                bf16x8 bh = *reinterpret_cast<const bf16x8*>(&Bh[kb][kgrp][fc * 16 + lrow][0]);
                bf16x8 bl = *reinterpret_cast<const bf16x8*>(&Bl[kb][kgrp][fc * 16 + lrow][0]);
                acc[fc] = __builtin_amdgcn_mfma_f32_16x16x32_bf16(af[kb], bh, acc[fc], 0, 0, 0);
                acc[fc] = __builtin_amdgcn_mfma_f32_16x16x32_bf16(af[kb], bl, acc[fc], 0, 0, 0);
            }
        }
        if (it + 1 < F_IN / 64) {
#pragma unroll
            for (int kb = 0; kb < 2; ++kb) {
                a_cur[kb][0] = a_nxt[kb][0];
                a_cur[kb][1] = a_nxt[kb][1];
            }
        }
    }

    // epilogue: bf16 Hp + fused per-head attention logits (fp32)
#pragma unroll
    for (int r = 0; r < 4; ++r) {
        int gr = row0 + wid * 16 + kgrp * 4 + r;
        float hv[4], sp[4], dp[4];
#pragma unroll
        for (int fc = 0; fc < 4; ++fc) {
            hv[fc] = acc[fc][r];
            sp[fc] = hv[fc] * ats[fc];
            dp[fc] = hv[fc] * atd[fc];
        }
#pragma unroll
        for (int mask = 1; mask <= 4; mask <<= 1) {
#pragma unroll
            for (int fc = 0; fc < 4; ++fc) {
                sp[fc] += __shfl_xor(sp[fc], mask);
                dp[fc] += __shfl_xor(dp[fc], mask);
            }
        }
        if (gr < Nn) {
#pragma unroll
            for (int fc = 0; fc < 4; ++fc)
                Hp[(size_t)gr * HD + fc * 16 + lrow] = (unsigned short)f2bf(hv[fc]);
            if ((lane & 7) == 0) {
                int hh = lrow >> 3;
#pragma unroll
                for (int fc = 0; fc < 4; ++fc) {
                    as1[gr * NHEAD + fc * 2 + hh] = sp[fc];
                    ad1[gr * NHEAD + fc * 2 + hh] = dp[fc];
                }
            }
        }
    }
}

// ---------------- agg1: 8 slots x 8 lanes; lane = head; fp32 h1 out ----------------
__global__ __launch_bounds__(256) void agg1_kernel(const unsigned short* __restrict__ Hp,
                                                   const float* __restrict__ as1,
                                                   const float* __restrict__ ad1,
                                                   const int* __restrict__ col,
                                                   const int* __restrict__ rp,
                                                   const float* __restrict__ b1,
                                                   float* __restrict__ h1, int Nn) {
    int n = blockIdx.x * 4 + (threadIdx.x >> 6);
    int lane = threadIdx.x & 63;
    if (n >= Nn) return;
    int slot = lane >> 3, j = lane & 7;   // j = head index, owns features j*8..j*8+7
    int beg = rp[n], end = rp[n + 1];
    float adv1 = ad1[n * NHEAD + j];
    float acc[8] = {0, 0, 0, 0, 0, 0, 0, 0};
    float dw = 0.f;
    for (int t = beg + slot; t < end; t += 8) {
        int s = col[t];
        float w = __expf(lrelu(as1[s * NHEAD + j] + adv1));
        dw += w;
        uint4 u = *reinterpret_cast<const uint4*>(&Hp[(size_t)s * HD + j * 8]);
        acc[0] += w * bfl(u.x); acc[1] += w * bfh(u.x);
        acc[2] += w * bfl(u.y); acc[3] += w * bfh(u.y);
        acc[4] += w * bfl(u.z); acc[5] += w * bfh(u.z);
        acc[6] += w * bfl(u.w); acc[7] += w * bfh(u.w);
    }
#pragma unroll
    for (int mask = 8; mask < 64; mask <<= 1) {
#pragma unroll
        for (int i = 0; i < 8; ++i) acc[i] += __shfl_xor(acc[i], mask);
        dw += __shfl_xor(dw, mask);
    }
    // self term + bias + ELU (all lanes; slot 0 writes)
    float w = __expf(lrelu(as1[n * NHEAD + j] + adv1));
    uint4 u = *reinterpret_cast<const uint4*>(&Hp[(size_t)n * HD + j * 8]);
    acc[0] += w * bfl(u.x); acc[1] += w * bfh(u.x);
    acc[2] += w * bfl(u.y); acc[3] += w * bfh(u.y);
    acc[4] += w * bfl(u.z); acc[5] += w * bfh(u.z);
    acc[6] += w * bfl(u.w); acc[7] += w * bfh(u.w);
    dw += w;
    float invd = 1.0f / (dw + 1e-16f);
    float4 b0 = *reinterpret_cast<const float4*>(&b1[j * 8]);
    float4 b4 = *reinterpret_cast<const float4*>(&b1[j * 8 + 4]);
    float bb[8] = {b0.x, b0.y, b0.z, b0.w, b4.x, b4.y, b4.z, b4.w};
#pragma unroll
    for (int i = 0; i < 8; ++i) {
        float v = acc[i] * invd + bb[i];
        acc[i] = v > 0.0f ? v : __expf(v) - 1.0f;
    }
    if (slot == 0) {
        float4 o0 = make_float4(acc[0], acc[1], acc[2], acc[3]);
        float4 o1 = make_float4(acc[4], acc[5], acc[6], acc[7]);
        *reinterpret_cast<float4*>(&h1[(size_t)n * HD + j * 8]) = o0;
        *reinterpret_cast<float4*>(&h1[(size_t)n * HD + j * 8 + 4]) = o1;
    }
}

// ---------------- GEMM2: tiled (64 rows/block) + fused alpha2, bf16 h2p out --------
#define G2R 64
__global__ __launch_bounds__(256) void gemm2_kernel(const float* __restrict__ H1,
                                                    const float* __restrict__ W2,
                                                    const float* __restrict__ asw,
                                                    const float* __restrict__ adw,
                                                    unsigned int* __restrict__ h2p,
                                                    float* __restrict__ as2,
                                                    float* __restrict__ ad2, int Nn) {
    __shared__ float Hs[G2R][HD + 1];
    __shared__ float W2s[HD][NC];
    __shared__ float asv[NC], adv[NC];
    int tid = threadIdx.x;
    for (int i = tid; i < HD * NC; i += 256) W2s[i / NC][i % NC] = W2[i];
    if (tid < NC) { asv[tid] = asw[tid]; adv[tid] = adw[tid]; }
    int row0 = blockIdx.x * G2R;
#pragma unroll
    for (int i = 0; i < 4; ++i) {
        int linear = i * 1024 + tid * 4;
        int r = linear >> 6, c = linear & 63;
        int gr = row0 + r;
        float4 v = make_float4(0.f, 0.f, 0.f, 0.f);
        if (gr < Nn) v = *reinterpret_cast<const float4*>(&H1[(size_t)gr * HD + c]);
        Hs[r][c + 0] = v.x; Hs[r][c + 1] = v.y; Hs[r][c + 2] = v.z; Hs[r][c + 3] = v.w;
    }
    __syncthreads();
    int row = tid >> 2, cg = tid & 3;      // 64 rows x 4 col-groups of 10
    int gr = row0 + row;
    float acc[10];
#pragma unroll
    for (int jj = 0; jj < 10; ++jj) acc[jj] = 0.0f;
    for (int k = 0; k < HD; ++k) {
        float a = Hs[row][k];
#pragma unroll
        for (int jj = 0; jj < 10; ++jj) acc[jj] += a * W2s[k][cg * 10 + jj];
    }
    float sa = 0.0f, da = 0.0f;
#pragma unroll
    for (int jj = 0; jj < 10; ++jj) {
        sa += acc[jj] * asv[cg * 10 + jj];
        da += acc[jj] * adv[cg * 10 + jj];
    }
    sa += __shfl_xor(sa, 1); sa += __shfl_xor(sa, 2);
    da += __shfl_xor(da, 1); da += __shfl_xor(da, 2);
    if (gr < Nn) {
        if (cg == 0) { as2[gr] = sa; ad2[gr] = da; }
#pragma unroll
        for (int jj = 0; jj < 5; ++jj) {
            unsigned int u = ((unsigned int)(unsigned short)f2bf(acc[2 * jj + 1]) << 16) |
                             (unsigned short)f2bf(acc[2 * jj]);
            h2p[(size_t)gr * 20 + cg * 5 + jj] = u;
        }
    }
}

// ---------------- agg2: bf16 gather + bias + log_softmax ----------------
__global__ __launch_bounds__(256) void agg2_kernel(const unsigned int* __restrict__ h2p,
                                                   const float* __restrict__ as2,
                                                   const float* __restrict__ ad2,
                                                   const int* __restrict__ col,
                                                   const int* __restrict__ rp,
                                                   const float* __restrict__ b2,
                                                   float* __restrict__ out, int Nn) {
    int n = blockIdx.x * 4 + (threadIdx.x >> 6);
    int lane = threadIdx.x & 63;
    if (n >= Nn) return;
    int slot = lane >> 4, l16 = lane & 15;
    bool act = l16 < 10;
    int beg = rp[n], end = rp[n + 1];
    float adv = ad2[n];
    float4 acc = make_float4(0.f, 0.f, 0.f, 0.f);
    float dw = 0.f;
    for (int t = beg + slot; t < end; t += 4) {
        int s = col[t];
        float w = __expf(lrelu(as2[s] + adv));
        dw += w;
        if (act) {
            uint2 u = *reinterpret_cast<const uint2*>(&h2p[(size_t)s * 20 + l16 * 2]);
            acc.x += w * bfl(u.x); acc.y += w * bfh(u.x);
            acc.z += w * bfl(u.y); acc.w += w * bfh(u.y);
        }
    }
#pragma unroll
    for (int mask = 16; mask < 64; mask <<= 1) {
        acc.x += __shfl_xor(acc.x, mask);
        acc.y += __shfl_xor(acc.y, mask);
        acc.z += __shfl_xor(acc.z, mask);
        acc.w += __shfl_xor(acc.w, mask);
        dw    += __shfl_xor(dw, mask);
    }
    float w = __expf(lrelu(as2[n] + adv));
    dw += w;
    float invd = 1.0f / (dw + 1e-16f);
    if (act) {
        uint2 u = *reinterpret_cast<const uint2*>(&h2p[(size_t)n * 20 + l16 * 2]);
        float4 bb = *reinterpret_cast<const float4*>(&b2[l16 * 4]);
        acc.x = (acc.x + w * bfl(u.x)) * invd + bb.x;
        acc.y = (acc.y + w * bfh(u.x)) * invd + bb.y;
        acc.z = (acc.z + w * bfl(u.y)) * invd + bb.z;
        acc.w = (acc.w + w * bfh(u.y)) * invd + bb.w;
    }
    float mloc = act ? fmaxf(fmaxf(acc.x, acc.y), fmaxf(acc.z, acc.w)) : -INFINITY;
#pragma unroll
    for (int mask = 1; mask < 16; mask <<= 1) mloc = fmaxf(mloc, __shfl_xor(mloc, mask));
    float s4 = act ? (__expf(acc.x - mloc) + __expf(acc.y - mloc) +
                      __expf(acc.z - mloc) + __expf(acc.w - mloc)) : 0.0f;
#pragma unroll
    for (int mask = 1; mask < 16; mask <<= 1) s4 += __shfl_xor(s4, mask);
    float lse = mloc + __logf(s4);
    if (slot == 0 && act) {
        float4 o = make_float4(acc.x - lse, acc.y - lse, acc.z - lse, acc.w - lse);
        *reinterpret_cast<float4*>(&out[(size_t)n * NC + l16 * 4]) = o;
    }
}

extern "C" void kernel_launch(void* const* d_in, const int* in_sizes, int n_in,
                              void* d_out, int out_size, void* d_ws, size_t ws_size,
                              hipStream_t stream) {
    const float* x    = (const float*)d_in[0];
    const int*   ei   = (const int*)d_in[1];
    const float* W1   = (const float*)d_in[2];
    const float* as1w = (const float*)d_in[3];
    const float* ad1w = (const float*)d_in[4];
    const float* b1   = (const float*)d_in[5];
    const float* W2   = (const float*)d_in[6];
    const float* as2w = (const float*)d_in[7];
    const float* ad2w = (const float*)d_in[8];
    const float* b2   = (const float*)d_in[9];
    float* out = (float*)d_out;

    int Nn = in_sizes[0] / F_IN;
    int E  = in_sizes[1] / 2;
    const int* srcv = ei;
    const int* dstv = ei + E;

    char* ws = (char*)d_ws;
    size_t off = 0;
    auto alloc = [&](size_t bytes) { size_t cur = off; off += (bytes + 255) & ~255ULL; return cur; };
    unsigned short* Hp = (unsigned short*)(ws + alloc((size_t)Nn * HD * 2));
    float* h1   = (float*)(ws + alloc((size_t)Nn * HD * 4));
    float* as1v = (float*)(ws + alloc((size_t)Nn * NHEAD * 4));
    float* ad1v = (float*)(ws + alloc((size_t)Nn * NHEAD * 4));
    unsigned int* h2p = (unsigned int*)(ws + alloc((size_t)Nn * 20 * 4));
    float* as2v = (float*)(ws + alloc((size_t)Nn * 4));
    float* ad2v = (float*)(ws + alloc((size_t)Nn * 4));
    int* deg  = (int*)(ws + alloc((size_t)Nn * 4));
    int* incl = (int*)(ws + alloc((size_t)Nn * 4));
    int* rp   = (int*)(ws + alloc((size_t)(Nn + 1) * 4));
    int* pos  = (int*)(ws + alloc((size_t)E * 4));
    int* col  = (int*)(ws + alloc((size_t)E * 4));
    int* bsum = (int*)(ws + alloc(256 * 4));

    int nb   = (Nn + 1023) / 1024;
    int nG1  = (Nn + G1_BM - 1) / G1_BM;
    int nCNT = (E + 255) / 256;

    zero_kernel<<<(Nn + 255) / 256, 256, 0, stream>>>(deg, Nn);
    g1c_kernel<<<nG1 + nCNT, 256, 0, stream>>>(x, W1, as1w, ad1w, Hp, as1v, ad1v,
                                               dstv, deg, pos, Nn, E, nG1);
    scanA_kernel<<<nb, 256, 0, stream>>>(deg, incl, bsum, Nn);
    scanB_kernel<<<1, 64, 0, stream>>>(bsum, nb);
    scanC_kernel<<<(Nn + 255) / 256, 256, 0, stream>>>(incl, bsum, rp, Nn);
    scatter_kernel<<<(E + 255) / 256, 256, 0, stream>>>(srcv, dstv, pos, rp, col, E);

    agg1_kernel<<<(Nn + 3) / 4, 256, 0, stream>>>(Hp, as1v, ad1v, col, rp, b1, h1, Nn);
    gemm2_kernel<<<(Nn + G2R - 1) / G2R, 256, 0, stream>>>(h1, W2, as2w, ad2w, h2p, as2v, ad2v, Nn);
    agg2_kernel<<<(Nn + 3) / 4, 256, 0, stream>>>(h2p, as2v, ad2v, col, rp, b2, out, Nn);
}